// Round 1
// baseline (1032.851 us; speedup 1.0000x reference)
//
#include <hip/hip_runtime.h>
#include <cstdint>
#include <cstddef>

// ---------- problem constants ----------
#define BB    8
#define SS    4096
#define DD    1280
#define CC    2048
#define HH    20
#define DH    64
#define LTXT  77
#define LIMG  16
#define MQ    (BB * SS)       // 32768
#define MTXT  (BB * LTXT)     // 616
#define MIMG  (BB * LIMG)     // 128

typedef unsigned short u16;
typedef __bf16 bf16x8 __attribute__((ext_vector_type(8)));
typedef unsigned short u16x8 __attribute__((ext_vector_type(8)));
typedef unsigned short u16x4 __attribute__((ext_vector_type(4)));
typedef float f32x4 __attribute__((ext_vector_type(4)));

#define MFMA_BF16(a, b, c) __builtin_amdgcn_mfma_f32_16x16x32_bf16((a), (b), (c), 0, 0, 0)

__device__ __forceinline__ u16 f2bf(float f) {
  union { float f; uint32_t u; } v; v.f = f;
  return (u16)((v.u + 0x7FFFu + ((v.u >> 16) & 1u)) >> 16);
}

__device__ __forceinline__ bf16x8 ld_bf8(const u16* p) {
  return __builtin_bit_cast(bf16x8, *(const u16x8*)p);
}

// async global->LDS, 16B per lane; LDS dest = wave-uniform base + lane*16
__device__ __forceinline__ void async16(const void* g, void* l) {
  __builtin_amdgcn_global_load_lds(
      (__attribute__((address_space(1))) void*)(uintptr_t)g,
      (__attribute__((address_space(3))) void*)(uintptr_t)l,
      16, 0, 0);
}

// =====================================================================
// prep: casts + weight transpose-casts, one launch, blockIdx.y = segment
// =====================================================================
__global__ void prep_kernel(
    const float* __restrict__ hidden, const float* __restrict__ txt,
    const float* __restrict__ ids, const float* __restrict__ hair,
    const float* __restrict__ Wq, const float* __restrict__ Wk,
    const float* __restrict__ Wv, const float* __restrict__ Wo,
    const float* __restrict__ Wk_id, const float* __restrict__ Wv_id,
    const float* __restrict__ Wk_hair, const float* __restrict__ Wv_hair,
    u16* __restrict__ hiddenB, u16* __restrict__ WqT, u16* __restrict__ WoT,
    u16* __restrict__ WkvTt, u16* __restrict__ WkvTi, u16* __restrict__ WkvTh,
    u16* __restrict__ stT, u16* __restrict__ stI, u16* __restrict__ stH)
{
  const int seg = blockIdx.y;
  const int64_t i0 = (int64_t)blockIdx.x * blockDim.x + threadIdx.x;
  const int64_t stride = (int64_t)gridDim.x * blockDim.x;

  switch (seg) {
    case 0: {  // hidden cast, vectorized x4
      const float4* src = (const float4*)hidden;
      u16x4* dst = (u16x4*)hiddenB;
      const int64_t n4 = (int64_t)MQ * DD / 4;
      for (int64_t i = i0; i < n4; i += stride) {
        float4 v = src[i];
        u16x4 o; o.x = f2bf(v.x); o.y = f2bf(v.y); o.z = f2bf(v.z); o.w = f2bf(v.w);
        dst[i] = o;
      }
      break;
    }
    case 1: {  // Wq [1280,1280] -> WqT [n][k]
      const int64_t n = (int64_t)DD * DD;
      for (int64_t i = i0; i < n; i += stride) {
        int nn = (int)(i / DD), kk = (int)(i - (int64_t)nn * DD);
        WqT[i] = f2bf(Wq[(int64_t)kk * DD + nn]);
      }
      break;
    }
    case 2: {
      const int64_t n = (int64_t)DD * DD;
      for (int64_t i = i0; i < n; i += stride) {
        int nn = (int)(i / DD), kk = (int)(i - (int64_t)nn * DD);
        WoT[i] = f2bf(Wo[(int64_t)kk * DD + nn]);
      }
      break;
    }
    case 3: case 4: case 5: case 6: case 7: case 8: {
      // KV weight halves: in [2048,1280] -> out half [1280][2048]
      const float* W = (seg == 3) ? Wk : (seg == 4) ? Wv : (seg == 5) ? Wk_id :
                       (seg == 6) ? Wv_id : (seg == 7) ? Wk_hair : Wv_hair;
      u16* out = (seg <= 4) ? WkvTt : (seg <= 6) ? WkvTi : WkvTh;
      const int64_t halfOff = (seg == 4 || seg == 6 || seg == 8) ? (int64_t)DD * CC : 0;
      const int64_t n = (int64_t)DD * CC;
      for (int64_t i = i0; i < n; i += stride) {
        int nn = (int)(i >> 11), kk = (int)(i & 2047);
        out[halfOff + i] = f2bf(W[(int64_t)kk * DD + nn]);
      }
      break;
    }
    case 9: {
      const int64_t n = (int64_t)MTXT * CC;
      for (int64_t i = i0; i < n; i += stride) stT[i] = f2bf(txt[i]);
      break;
    }
    case 10: {
      const int64_t n = (int64_t)MIMG * CC;
      for (int64_t i = i0; i < n; i += stride) stI[i] = f2bf(ids[i]);
      break;
    }
    default: {
      const int64_t n = (int64_t)MIMG * CC;
      for (int64_t i = i0; i < n; i += stride) stH[i] = f2bf(hair[i]);
      break;
    }
  }
}

// =====================================================================
// GEMM: C[M,N] = A[M,K]bf16 * Bt[N,K]bf16 ; 128x128 tile, BK=32,
// 256 thr = 4 waves in 2x2, each wave 64x64 via 4x4 of 16x16x32 MFMA.
// OUT_MODE 0: bf16 store * outScale ; 1: fp32 store + biasScale*bias[col]
// =====================================================================
template<int OUT_MODE>
__device__ __forceinline__ void gemm_tile_body(
    const u16* __restrict__ A, const u16* __restrict__ Bt, void* __restrict__ Cv,
    int M, int N, int K, int tm, int tn,
    float outScale, const float* __restrict__ bias, float biasScale)
{
  __shared__ u16 As[128 * 32];
  __shared__ u16 Bs[128 * 32];

  const int tid = threadIdx.x;
  const int w  = tid >> 6;
  const int l  = tid & 63;
  const int q4 = l >> 4;
  const int lm = l & 15;
  const int wM = w & 1;
  const int wN = w >> 1;

  int rA0 = tm * 128 + w * 32 + (l >> 2);
  int rA1 = rA0 + 16;
  if (rA0 > M - 1) rA0 = M - 1;   // edge tiles: clamp (epilogue masks rows>=M)
  if (rA1 > M - 1) rA1 = M - 1;
  const int cc = (l & 3) * 8;
  const u16* gA0 = A + (size_t)rA0 * K + cc;
  const u16* gA1 = A + (size_t)rA1 * K + cc;
  const int rB = tn * 128 + w * 32 + (l >> 2);
  const u16* gB0 = Bt + (size_t)rB * K + cc;
  const u16* gB1 = gB0 + (size_t)16 * K;
  u16* lA0 = As + (w * 32) * 32;
  u16* lA1 = As + (w * 32 + 16) * 32;
  u16* lB0 = Bs + (w * 32) * 32;
  u16* lB1 = Bs + (w * 32 + 16) * 32;

  f32x4 acc[4][4] = {};

  for (int k0 = 0; k0 < K; k0 += 32) {
    async16(gA0, lA0);
    async16(gA1, lA1);
    async16(gB0, lB0);
    async16(gB1, lB1);
    gA0 += 32; gA1 += 32; gB0 += 32; gB1 += 32;
    __syncthreads();   // compiler emits vmcnt(0) drain before s_barrier
    bf16x8 af[4], bfr[4];
#pragma unroll
    for (int i = 0; i < 4; i++) {
      af[i]  = ld_bf8(As + (wM * 64 + i * 16 + lm) * 32 + q4 * 8);
      bfr[i] = ld_bf8(Bs + (wN * 64 + i * 16 + lm) * 32 + q4 * 8);
    }
#pragma unroll
    for (int i = 0; i < 4; i++)
#pragma unroll
      for (int j = 0; j < 4; j++)
        acc[i][j] = MFMA_BF16(af[i], bfr[j], acc[i][j]);
    __syncthreads();
  }

  if constexpr (OUT_MODE == 0) {
    u16* C = (u16*)Cv;
#pragma unroll
    for (int i = 0; i < 4; i++)
#pragma unroll
      for (int r = 0; r < 4; r++) {
        const int row = tm * 128 + wM * 64 + i * 16 + q4 * 4 + r;
        if (row < M) {
          u16* cp = C + (size_t)row * N + tn * 128 + wN * 64 + lm;
#pragma unroll
          for (int j = 0; j < 4; j++)
            cp[j * 16] = f2bf(acc[i][j][r] * outScale);
        }
      }
  } else {
    float* C = (float*)Cv;
    float bs[4];
#pragma unroll
    for (int j = 0; j < 4; j++)
      bs[j] = biasScale * bias[tn * 128 + wN * 64 + j * 16 + lm];
#pragma unroll
    for (int i = 0; i < 4; i++)
#pragma unroll
      for (int r = 0; r < 4; r++) {
        const int row = tm * 128 + wM * 64 + i * 16 + q4 * 4 + r;
        if (row < M) {
          float* cp = C + (size_t)row * N + tn * 128 + wN * 64 + lm;
#pragma unroll
          for (int j = 0; j < 4; j++)
            cp[j * 16] = acc[i][j][r] + bs[j];
        }
      }
  }
}

__global__ __launch_bounds__(256, 2) void gemm_bf16_out(
    const u16* __restrict__ A, const u16* __restrict__ Bt, u16* __restrict__ C,
    int M, int N, int K, float scale)
{
  gemm_tile_body<0>(A, Bt, C, M, N, K, blockIdx.x, blockIdx.y, scale, nullptr, 0.f);
}

__global__ __launch_bounds__(256, 2) void gemm_f32_bias(
    const u16* __restrict__ A, const u16* __restrict__ Bt, float* __restrict__ C,
    int M, int N, int K, const float* __restrict__ bias, float biasScale)
{
  gemm_tile_body<1>(A, Bt, C, M, N, K, blockIdx.x, blockIdx.y, 1.f, bias, biasScale);
}

// three KV-projection GEMMs in one launch (blockIdx.z = branch)
__global__ __launch_bounds__(256, 2) void gemm_kv3(
    const u16* A0, const u16* A1, const u16* A2,
    const u16* B0, const u16* B1, const u16* B2,
    u16* C0, u16* C1, u16* C2, int M0, int M1, int M2)
{
  const int z = blockIdx.z;
  const u16* A  = (z == 0) ? A0 : (z == 1) ? A1 : A2;
  const u16* Bt = (z == 0) ? B0 : (z == 1) ? B1 : B2;
  u16* C        = (z == 0) ? C0 : (z == 1) ? C1 : C2;
  const int M   = (z == 0) ? M0 : (z == 1) ? M1 : M2;
  if ((int)blockIdx.x * 128 >= M) return;  // uniform early-out, before any barrier
  gemm_tile_body<0>(A, Bt, C, M, 2 * DD, CC, blockIdx.x, blockIdx.y, 1.f, nullptr, 0.f);
}

// =====================================================================
// fused 3-branch attention. Q pre-scaled by 0.125. One block = one
// (b,h,64-query tile); 4 waves, each wave owns 16 queries.
// LDS strides padded so b128 reads land 2-way max (free per m136).
// =====================================================================
constexpr int KS  = 72;   // K row stride   (lane stride 144B -> 2-way)
constexpr int VST = 104;  // V^T text stride (208B -> 2-way)
constexpr int VSI = 40;   // V^T img stride  (80B  -> 2-way)
constexpr int PS  = 104;  // P row stride

template<int NT, int L, int KP, int VS>
__device__ __forceinline__ void attn_branch(
    const u16* __restrict__ Klds, const u16* __restrict__ Vlds, u16* __restrict__ Pw,
    const bf16x8& qf0, const bf16x8& qf1, int lm, int q4, f32x4* acc)
{
  // scores: D[q=row][key=col], q = q4*4+r, key = nt*16+lm
  f32x4 sc[NT];
#pragma unroll
  for (int nt = 0; nt < NT; nt++) {
    f32x4 c = {};
    c = MFMA_BF16(qf0, ld_bf8(Klds + (nt * 16 + lm) * KS + q4 * 8), c);
    c = MFMA_BF16(qf1, ld_bf8(Klds + (nt * 16 + lm) * KS + 32 + q4 * 8), c);
    sc[nt] = c;
  }
  // row max (over tiles, then over the 16 lanes of the quad)
  float mx[4] = {-3e38f, -3e38f, -3e38f, -3e38f};
#pragma unroll
  for (int nt = 0; nt < NT; nt++) {
    const bool valid = (nt * 16 + lm) < L;
#pragma unroll
    for (int r = 0; r < 4; r++)
      if (valid) mx[r] = fmaxf(mx[r], sc[nt][r]);
  }
#pragma unroll
  for (int r = 0; r < 4; r++) {
    mx[r] = fmaxf(mx[r], __shfl_xor(mx[r], 1));
    mx[r] = fmaxf(mx[r], __shfl_xor(mx[r], 2));
    mx[r] = fmaxf(mx[r], __shfl_xor(mx[r], 4));
    mx[r] = fmaxf(mx[r], __shfl_xor(mx[r], 8));
  }
  float sm[4] = {0.f, 0.f, 0.f, 0.f};
#pragma unroll
  for (int nt = 0; nt < NT; nt++) {
    const bool valid = (nt * 16 + lm) < L;
#pragma unroll
    for (int r = 0; r < 4; r++) {
      float e = valid ? __expf(sc[nt][r] - mx[r]) : 0.f;
      sc[nt][r] = e;
      sm[r] += e;
    }
  }
#pragma unroll
  for (int r = 0; r < 4; r++) {
    sm[r] += __shfl_xor(sm[r], 1);
    sm[r] += __shfl_xor(sm[r], 2);
    sm[r] += __shfl_xor(sm[r], 4);
    sm[r] += __shfl_xor(sm[r], 8);
  }
  float inv[4];
#pragma unroll
  for (int r = 0; r < 4; r++) inv[r] = 1.0f / sm[r];
  // P: C-layout -> LDS (A-layout round trip, m120 pattern)
#pragma unroll
  for (int nt = 0; nt < NT; nt++)
#pragma unroll
    for (int r = 0; r < 4; r++)
      Pw[(q4 * 4 + r) * PS + nt * 16 + lm] = f2bf(sc[nt][r] * inv[r]);
  if (NT * 16 < KP) {  // zero stale cols (img branches: cols 16..31)
#pragma unroll
    for (int r = 0; r < 4; r++)
      Pw[(q4 * 4 + r) * PS + NT * 16 + lm] = 0;
  }
  __syncthreads();
  // O += P @ V  (A = P rows, B = V^T rows = dh)
#pragma unroll
  for (int kt = 0; kt < KP / 32; kt++) {
    const bf16x8 af = ld_bf8(Pw + lm * PS + kt * 32 + q4 * 8);
#pragma unroll
    for (int d = 0; d < 4; d++)
      acc[d] = MFMA_BF16(af, ld_bf8(Vlds + (d * 16 + lm) * VS + kt * 32 + q4 * 8), acc[d]);
  }
  __syncthreads();
}

__global__ __launch_bounds__(256, 2) void attn_kernel(
    const u16* __restrict__ Qb, const u16* __restrict__ kvT,
    const u16* __restrict__ kvI, const u16* __restrict__ kvH,
    u16* __restrict__ Ob)
{
  __shared__ u16 Kt[80 * KS];
  __shared__ u16 Vt[64 * VST];
  __shared__ u16 Ki[16 * KS];
  __shared__ u16 Kh[16 * KS];
  __shared__ u16 Vi[64 * VSI];
  __shared__ u16 Vh[64 * VSI];
  __shared__ u16 Pl[4][16 * PS];

  const int qt = blockIdx.x, h = blockIdx.y, b = blockIdx.z;
  const int tid = threadIdx.x;
  const int w  = tid >> 6;
  const int l  = tid & 63;
  const int q4 = l >> 4;
  const int lm = l & 15;

  for (int i = tid; i < 80 * 64; i += 256) {
    const int key = i >> 6, dh = i & 63;
    Kt[key * KS + dh] = (key < LTXT)
        ? kvT[((size_t)(b * LTXT + key)) * (2 * DD) + h * 64 + dh] : (u16)0;
  }
  for (int i = tid; i < 64 * 96; i += 256) {
    const int dh = i / 96, key = i % 96;
    Vt[dh * VST + key] = (key < LTXT)
        ? kvT[((size_t)(b * LTXT + key)) * (2 * DD) + DD + h * 64 + dh] : (u16)0;
  }
  for (int i = tid; i < 16 * 64; i += 256) {
    const int key = i >> 6, dh = i & 63;
    Ki[key * KS + dh] = kvI[((size_t)(b * LIMG + key)) * (2 * DD) + h * 64 + dh];
    Kh[key * KS + dh] = kvH[((size_t)(b * LIMG + key)) * (2 * DD) + h * 64 + dh];
  }
  for (int i = tid; i < 64 * 32; i += 256) {
    const int dh = i >> 5, key = i & 31;
    Vi[dh * VSI + key] = (key < LIMG)
        ? kvI[((size_t)(b * LIMG + key)) * (2 * DD) + DD + h * 64 + dh] : (u16)0;
    Vh[dh * VSI + key] = (key < LIMG)
        ? kvH[((size_t)(b * LIMG + key)) * (2 * DD) + DD + h * 64 + dh] : (u16)0;
  }
  for (int i = tid; i < 16 * PS; i += 256) {
    Pl[0][i] = 0; Pl[1][i] = 0; Pl[2][i] = 0; Pl[3][i] = 0;
  }
  __syncthreads();

  const int srow = qt * 64 + w * 16 + lm;
  const u16* qp = Qb + ((size_t)(b * SS + srow)) * DD + h * 64 + q4 * 8;
  const bf16x8 qf0 = ld_bf8(qp);
  const bf16x8 qf1 = ld_bf8(qp + 32);

  f32x4 acc[4] = {};

  attn_branch<5, LTXT, 96, VST>(Kt, Vt, Pl[w], qf0, qf1, lm, q4, acc);
  attn_branch<1, LIMG, 32, VSI>(Ki, Vi, Pl[w], qf0, qf1, lm, q4, acc);
  attn_branch<1, LIMG, 32, VSI>(Kh, Vh, Pl[w], qf0, qf1, lm, q4, acc);

#pragma unroll
  for (int d = 0; d < 4; d++)
#pragma unroll
    for (int r = 0; r < 4; r++) {
      const int row = qt * 64 + w * 16 + q4 * 4 + r;
      Ob[((size_t)(b * SS + row)) * DD + h * 64 + d * 16 + lm] = f2bf(acc[d][r]);
    }
}

// =====================================================================
extern "C" void kernel_launch(void* const* d_in, const int* in_sizes, int n_in,
                              void* d_out, int out_size, void* d_ws, size_t ws_size,
                              hipStream_t stream) {
  (void)in_sizes; (void)n_in; (void)out_size; (void)ws_size;
  const float* hidden  = (const float*)d_in[0];
  const float* txt     = (const float*)d_in[1];
  const float* ids     = (const float*)d_in[2];
  const float* hair    = (const float*)d_in[3];
  const float* Wq      = (const float*)d_in[4];
  const float* Wk      = (const float*)d_in[5];
  const float* Wv      = (const float*)d_in[6];
  const float* Wo      = (const float*)d_in[7];
  const float* bo      = (const float*)d_in[8];
  const float* Wk_id   = (const float*)d_in[9];
  const float* Wv_id   = (const float*)d_in[10];
  const float* Wk_hair = (const float*)d_in[11];
  const float* Wv_hair = (const float*)d_in[12];
  float* out = (float*)d_out;

  char* ws = (char*)d_ws;
  size_t off = 0;
  auto alloc = [&](size_t bytes) {
    void* p = ws + off;
    off = (off + bytes + 255) & ~(size_t)255;
    return p;
  };
  u16* hiddenB = (u16*)alloc((size_t)MQ * DD * 2);       // 83.9 MB
  u16* QB      = (u16*)alloc((size_t)MQ * DD * 2);       // 83.9 MB
  u16* OB      = (u16*)alloc((size_t)MQ * DD * 2);       // 83.9 MB
  u16* WqT     = (u16*)alloc((size_t)DD * DD * 2);
  u16* WoT     = (u16*)alloc((size_t)DD * DD * 2);
  u16* WkvTt   = (u16*)alloc((size_t)2 * DD * CC * 2);
  u16* WkvTi   = (u16*)alloc((size_t)2 * DD * CC * 2);
  u16* WkvTh   = (u16*)alloc((size_t)2 * DD * CC * 2);
  u16* stT     = (u16*)alloc((size_t)MTXT * CC * 2);
  u16* stI     = (u16*)alloc((size_t)MIMG * CC * 2);
  u16* stH     = (u16*)alloc((size_t)MIMG * CC * 2);
  u16* kvT     = (u16*)alloc((size_t)MTXT * 2 * DD * 2);
  u16* kvI     = (u16*)alloc((size_t)MIMG * 2 * DD * 2);
  u16* kvH     = (u16*)alloc((size_t)MIMG * 2 * DD * 2);
  // total ~284 MB of workspace

  prep_kernel<<<dim3(1024, 12), 256, 0, stream>>>(
      hidden, txt, ids, hair, Wq, Wk, Wv, Wo, Wk_id, Wv_id, Wk_hair, Wv_hair,
      hiddenB, WqT, WoT, WkvTt, WkvTi, WkvTh, stT, stI, stH);

  // Q = hidden @ Wq, scaled by 1/sqrt(DH)=0.125 (exact in bf16)
  gemm_bf16_out<<<dim3(MQ / 128, DD / 128), 256, 0, stream>>>(
      hiddenB, WqT, QB, MQ, DD, DD, 0.125f);

  // K|V projections for all three branches
  gemm_kv3<<<dim3((MTXT + 127) / 128, (2 * DD) / 128, 3), 256, 0, stream>>>(
      stT, stI, stH, WkvTt, WkvTi, WkvTh, kvT, kvI, kvH, MTXT, MIMG, MIMG);

  // fused 3-branch attention -> summed O (bf16)
  attn_kernel<<<dim3(SS / 64, HH, BB), 256, 0, stream>>>(QB, kvT, kvI, kvH, OB);

  // out = O_sum @ Wo + 3*bo (fp32)
  gemm_f32_bias<<<dim3(MQ / 128, DD / 128), 256, 0, stream>>>(
      OB, WoT, out, MQ, DD, DD, bo, 3.0f);
}

// Round 2
// 832.984 us; speedup vs baseline: 1.2399x; 1.2399x over previous
//
#include <hip/hip_runtime.h>
#include <cstdint>
#include <cstddef>

// ---------- problem constants ----------
#define BB    8
#define SS    4096
#define DD    1280
#define CC    2048
#define HH    20
#define DH    64
#define LTXT  77
#define LIMG  16
#define MQ    (BB * SS)       // 32768
#define MTXT  (BB * LTXT)     // 616
#define MIMG  (BB * LIMG)     // 128

typedef unsigned short u16;
typedef __bf16 bf16x8 __attribute__((ext_vector_type(8)));
typedef unsigned short u16x8 __attribute__((ext_vector_type(8)));
typedef unsigned short u16x4 __attribute__((ext_vector_type(4)));
typedef float f32x4 __attribute__((ext_vector_type(4)));

#define MFMA_BF16(a, b, c) __builtin_amdgcn_mfma_f32_16x16x32_bf16((a), (b), (c), 0, 0, 0)

__device__ __forceinline__ u16 f2bf(float f) {
  union { float f; uint32_t u; } v; v.f = f;
  return (u16)((v.u + 0x7FFFu + ((v.u >> 16) & 1u)) >> 16);
}

__device__ __forceinline__ bf16x8 ld_bf8(const u16* p) {
  return __builtin_bit_cast(bf16x8, *(const u16x8*)p);
}

// async global->LDS, 16B per lane; LDS dest = wave-uniform base + lane*16
__device__ __forceinline__ void async16(const void* g, void* l) {
  __builtin_amdgcn_global_load_lds(
      (__attribute__((address_space(1))) void*)(uintptr_t)g,
      (__attribute__((address_space(3))) void*)(uintptr_t)l,
      16, 0, 0);
}

// =====================================================================
// prep: casts + weight transpose-casts, one launch, blockIdx.y = segment
// =====================================================================
__global__ void prep_kernel(
    const float* __restrict__ hidden, const float* __restrict__ txt,
    const float* __restrict__ ids, const float* __restrict__ hair,
    const float* __restrict__ Wq, const float* __restrict__ Wk,
    const float* __restrict__ Wv, const float* __restrict__ Wo,
    const float* __restrict__ Wk_id, const float* __restrict__ Wv_id,
    const float* __restrict__ Wk_hair, const float* __restrict__ Wv_hair,
    u16* __restrict__ hiddenB, u16* __restrict__ WqT, u16* __restrict__ WoT,
    u16* __restrict__ WkvTt, u16* __restrict__ WkvTi, u16* __restrict__ WkvTh,
    u16* __restrict__ stT, u16* __restrict__ stI, u16* __restrict__ stH)
{
  const int seg = blockIdx.y;
  const int64_t i0 = (int64_t)blockIdx.x * blockDim.x + threadIdx.x;
  const int64_t stride = (int64_t)gridDim.x * blockDim.x;

  switch (seg) {
    case 0: {  // hidden cast, vectorized x4
      const float4* src = (const float4*)hidden;
      u16x4* dst = (u16x4*)hiddenB;
      const int64_t n4 = (int64_t)MQ * DD / 4;
      for (int64_t i = i0; i < n4; i += stride) {
        float4 v = src[i];
        u16x4 o; o.x = f2bf(v.x); o.y = f2bf(v.y); o.z = f2bf(v.z); o.w = f2bf(v.w);
        dst[i] = o;
      }
      break;
    }
    case 1: {  // Wq [1280,1280] -> WqT [n][k]
      const int64_t n = (int64_t)DD * DD;
      for (int64_t i = i0; i < n; i += stride) {
        int nn = (int)(i / DD), kk = (int)(i - (int64_t)nn * DD);
        WqT[i] = f2bf(Wq[(int64_t)kk * DD + nn]);
      }
      break;
    }
    case 2: {
      const int64_t n = (int64_t)DD * DD;
      for (int64_t i = i0; i < n; i += stride) {
        int nn = (int)(i / DD), kk = (int)(i - (int64_t)nn * DD);
        WoT[i] = f2bf(Wo[(int64_t)kk * DD + nn]);
      }
      break;
    }
    case 3: case 4: case 5: case 6: case 7: case 8: {
      // KV weight halves: in [2048,1280] -> out half [1280][2048]
      const float* W = (seg == 3) ? Wk : (seg == 4) ? Wv : (seg == 5) ? Wk_id :
                       (seg == 6) ? Wv_id : (seg == 7) ? Wk_hair : Wv_hair;
      u16* out = (seg <= 4) ? WkvTt : (seg <= 6) ? WkvTi : WkvTh;
      const int64_t halfOff = (seg == 4 || seg == 6 || seg == 8) ? (int64_t)DD * CC : 0;
      const int64_t n = (int64_t)DD * CC;
      for (int64_t i = i0; i < n; i += stride) {
        int nn = (int)(i >> 11), kk = (int)(i & 2047);
        out[halfOff + i] = f2bf(W[(int64_t)kk * DD + nn]);
      }
      break;
    }
    case 9: {
      const int64_t n = (int64_t)MTXT * CC;
      for (int64_t i = i0; i < n; i += stride) stT[i] = f2bf(txt[i]);
      break;
    }
    case 10: {
      const int64_t n = (int64_t)MIMG * CC;
      for (int64_t i = i0; i < n; i += stride) stI[i] = f2bf(ids[i]);
      break;
    }
    default: {
      const int64_t n = (int64_t)MIMG * CC;
      for (int64_t i = i0; i < n; i += stride) stH[i] = f2bf(hair[i]);
      break;
    }
  }
}

// =====================================================================
// GEMM: C[M,N] = A[M,K]bf16 * Bt[N,K]bf16 ; 128x128 tile, BK=32,
// 256 thr = 4 waves in 2x2, each wave 64x64 via 4x4 of 16x16x32 MFMA.
// OUT_MODE 0: bf16 store * outScale ; 1: fp32 store + biasScale*bias[col]
// =====================================================================
template<int OUT_MODE>
__device__ __forceinline__ void gemm_tile_body(
    const u16* __restrict__ A, const u16* __restrict__ Bt, void* __restrict__ Cv,
    int M, int N, int K, int tm, int tn,
    float outScale, const float* __restrict__ bias, float biasScale)
{
  __shared__ u16 As[128 * 32];
  __shared__ u16 Bs[128 * 32];

  const int tid = threadIdx.x;
  const int w  = tid >> 6;
  const int l  = tid & 63;
  const int q4 = l >> 4;
  const int lm = l & 15;
  const int wM = w & 1;
  const int wN = w >> 1;

  int rA0 = tm * 128 + w * 32 + (l >> 2);
  int rA1 = rA0 + 16;
  if (rA0 > M - 1) rA0 = M - 1;   // edge tiles: clamp (epilogue masks rows>=M)
  if (rA1 > M - 1) rA1 = M - 1;
  const int cc = (l & 3) * 8;
  const u16* gA0 = A + (size_t)rA0 * K + cc;
  const u16* gA1 = A + (size_t)rA1 * K + cc;
  const int rB = tn * 128 + w * 32 + (l >> 2);
  const u16* gB0 = Bt + (size_t)rB * K + cc;
  const u16* gB1 = gB0 + (size_t)16 * K;
  u16* lA0 = As + (w * 32) * 32;
  u16* lA1 = As + (w * 32 + 16) * 32;
  u16* lB0 = Bs + (w * 32) * 32;
  u16* lB1 = Bs + (w * 32 + 16) * 32;

  f32x4 acc[4][4] = {};

  for (int k0 = 0; k0 < K; k0 += 32) {
    async16(gA0, lA0);
    async16(gA1, lA1);
    async16(gB0, lB0);
    async16(gB1, lB1);
    gA0 += 32; gA1 += 32; gB0 += 32; gB1 += 32;
    __syncthreads();   // compiler emits vmcnt(0) drain before s_barrier
    bf16x8 af[4], bfr[4];
#pragma unroll
    for (int i = 0; i < 4; i++) {
      af[i]  = ld_bf8(As + (wM * 64 + i * 16 + lm) * 32 + q4 * 8);
      bfr[i] = ld_bf8(Bs + (wN * 64 + i * 16 + lm) * 32 + q4 * 8);
    }
#pragma unroll
    for (int i = 0; i < 4; i++)
#pragma unroll
      for (int j = 0; j < 4; j++)
        acc[i][j] = MFMA_BF16(af[i], bfr[j], acc[i][j]);
    __syncthreads();
  }

  if constexpr (OUT_MODE == 0) {
    u16* C = (u16*)Cv;
#pragma unroll
    for (int i = 0; i < 4; i++)
#pragma unroll
      for (int r = 0; r < 4; r++) {
        const int row = tm * 128 + wM * 64 + i * 16 + q4 * 4 + r;
        if (row < M) {
          u16* cp = C + (size_t)row * N + tn * 128 + wN * 64 + lm;
#pragma unroll
          for (int j = 0; j < 4; j++)
            cp[j * 16] = f2bf(acc[i][j][r] * outScale);
        }
      }
  } else {
    float* C = (float*)Cv;
    float bs[4];
#pragma unroll
    for (int j = 0; j < 4; j++)
      bs[j] = biasScale * bias[tn * 128 + wN * 64 + j * 16 + lm];
#pragma unroll
    for (int i = 0; i < 4; i++)
#pragma unroll
      for (int r = 0; r < 4; r++) {
        const int row = tm * 128 + wM * 64 + i * 16 + q4 * 4 + r;
        if (row < M) {
          float* cp = C + (size_t)row * N + tn * 128 + wN * 64 + lm;
#pragma unroll
          for (int j = 0; j < 4; j++)
            cp[j * 16] = acc[i][j][r] + bs[j];
        }
      }
  }
}

__global__ __launch_bounds__(256, 2) void gemm_bf16_out(
    const u16* __restrict__ A, const u16* __restrict__ Bt, u16* __restrict__ C,
    int M, int N, int K, float scale)
{
  gemm_tile_body<0>(A, Bt, C, M, N, K, blockIdx.x, blockIdx.y, scale, nullptr, 0.f);
}

__global__ __launch_bounds__(256, 2) void gemm_f32_bias(
    const u16* __restrict__ A, const u16* __restrict__ Bt, float* __restrict__ C,
    int M, int N, int K, const float* __restrict__ bias, float biasScale)
{
  gemm_tile_body<1>(A, Bt, C, M, N, K, blockIdx.x, blockIdx.y, 1.f, bias, biasScale);
}

// three KV-projection GEMMs in one launch (blockIdx.z = branch)
__global__ __launch_bounds__(256, 2) void gemm_kv3(
    const u16* A0, const u16* A1, const u16* A2,
    const u16* B0, const u16* B1, const u16* B2,
    u16* C0, u16* C1, u16* C2, int M0, int M1, int M2)
{
  const int z = blockIdx.z;
  const u16* A  = (z == 0) ? A0 : (z == 1) ? A1 : A2;
  const u16* Bt = (z == 0) ? B0 : (z == 1) ? B1 : B2;
  u16* C        = (z == 0) ? C0 : (z == 1) ? C1 : C2;
  const int M   = (z == 0) ? M0 : (z == 1) ? M1 : M2;
  if ((int)blockIdx.x * 128 >= M) return;  // uniform early-out, before any barrier
  gemm_tile_body<0>(A, Bt, C, M, 2 * DD, CC, blockIdx.x, blockIdx.y, 1.f, nullptr, 0.f);
}

// =====================================================================
// fused 3-branch attention, v2.
//  - one block = (b, h, 256-query chunk): 4x fewer blocks than v1, KV
//    staged ONCE per 256 queries (vectorized u16x8 global loads).
//  - each wave owns 64 queries, processed as 4 sequential 16-row m-tiles;
//    per-m acc stored straight to global (keeps VGPRs low).
//  - NO block-wide barriers after staging: P round-trips through a
//    per-wave LDS buffer; same-wave ds ordering is compiler-enforced.
// =====================================================================
constexpr int KS  = 72;   // K row stride   (16B-aligned rows)
constexpr int VST = 104;  // V^T text stride (96 keys + 8 pad)
constexpr int VSI = 40;   // V^T img stride  (32 keys + 8 pad)
constexpr int PS  = 104;  // P row stride

template<int NT, int L, int KP, int VS>
__device__ __forceinline__ void attn_branch(
    const u16* __restrict__ Klds, const u16* __restrict__ Vlds, u16* __restrict__ Pw,
    const bf16x8& qf0, const bf16x8& qf1, int lm, int q4, f32x4* acc)
{
  // scores: D[q=row][key=col], q = q4*4+r, key = nt*16+lm
  f32x4 sc[NT];
#pragma unroll
  for (int nt = 0; nt < NT; nt++) {
    f32x4 c = {};
    c = MFMA_BF16(qf0, ld_bf8(Klds + (nt * 16 + lm) * KS + q4 * 8), c);
    c = MFMA_BF16(qf1, ld_bf8(Klds + (nt * 16 + lm) * KS + 32 + q4 * 8), c);
    sc[nt] = c;
  }
  // row max (over tiles, then over the 16 lanes of the quad)
  float mx[4] = {-3e38f, -3e38f, -3e38f, -3e38f};
#pragma unroll
  for (int nt = 0; nt < NT; nt++) {
    const bool valid = (nt * 16 + lm) < L;
#pragma unroll
    for (int r = 0; r < 4; r++)
      if (valid) mx[r] = fmaxf(mx[r], sc[nt][r]);
  }
#pragma unroll
  for (int r = 0; r < 4; r++) {
    mx[r] = fmaxf(mx[r], __shfl_xor(mx[r], 1));
    mx[r] = fmaxf(mx[r], __shfl_xor(mx[r], 2));
    mx[r] = fmaxf(mx[r], __shfl_xor(mx[r], 4));
    mx[r] = fmaxf(mx[r], __shfl_xor(mx[r], 8));
  }
  float sm[4] = {0.f, 0.f, 0.f, 0.f};
#pragma unroll
  for (int nt = 0; nt < NT; nt++) {
    const bool valid = (nt * 16 + lm) < L;
#pragma unroll
    for (int r = 0; r < 4; r++) {
      float e = valid ? __expf(sc[nt][r] - mx[r]) : 0.f;
      sc[nt][r] = e;
      sm[r] += e;
    }
  }
#pragma unroll
  for (int r = 0; r < 4; r++) {
    sm[r] += __shfl_xor(sm[r], 1);
    sm[r] += __shfl_xor(sm[r], 2);
    sm[r] += __shfl_xor(sm[r], 4);
    sm[r] += __shfl_xor(sm[r], 8);
  }
  float inv[4];
#pragma unroll
  for (int r = 0; r < 4; r++) inv[r] = 1.0f / sm[r];
  // P: C-layout -> per-wave LDS buffer (A-layout round trip, m120 pattern)
#pragma unroll
  for (int nt = 0; nt < NT; nt++)
#pragma unroll
    for (int r = 0; r < 4; r++)
      Pw[(q4 * 4 + r) * PS + nt * 16 + lm] = f2bf(sc[nt][r] * inv[r]);
  if (NT * 16 < KP) {  // zero pad cols (txt: 80..95, img: 16..31)
#pragma unroll
    for (int r = 0; r < 4; r++)
      Pw[(q4 * 4 + r) * PS + NT * 16 + lm] = 0;
  }
  // O += P @ V  (A = P rows, B = V^T rows = dh); same-wave LDS dependency,
  // ordering via compiler-inserted lgkmcnt waits — no barrier needed.
#pragma unroll
  for (int kt = 0; kt < KP / 32; kt++) {
    const bf16x8 af = ld_bf8(Pw + lm * PS + kt * 32 + q4 * 8);
#pragma unroll
    for (int d = 0; d < 4; d++)
      acc[d] = MFMA_BF16(af, ld_bf8(Vlds + (d * 16 + lm) * VS + kt * 32 + q4 * 8), acc[d]);
  }
}

__global__ __launch_bounds__(256, 2) void attn_kernel(
    const u16* __restrict__ Qb, const u16* __restrict__ kvT,
    const u16* __restrict__ kvI, const u16* __restrict__ kvH,
    u16* __restrict__ Ob)
{
  __shared__ u16 Kt[80 * KS];
  __shared__ u16 Vt[64 * VST];
  __shared__ u16 Ki[16 * KS];
  __shared__ u16 Kh[16 * KS];
  __shared__ u16 Vi[64 * VSI];
  __shared__ u16 Vh[64 * VSI];
  __shared__ u16 Pl[4][16 * PS];

  const int qt = blockIdx.x, h = blockIdx.y, b = blockIdx.z;
  const int tid = threadIdx.x;

  // ---- staging (vectorized; all branches at once) ----
  // K text: 80 rows x 64 dh = 640 u16x8 units
  for (int i = tid; i < 640; i += 256) {
    const int key = i >> 3, g = i & 7;
    u16x8 v = {};
    if (key < LTXT)
      v = *(const u16x8*)(kvT + (size_t)(b * LTXT + key) * (2 * DD) + h * 64 + g * 8);
    *(u16x8*)(Kt + key * KS + g * 8) = v;
  }
  // K id / hair: 16 rows x 8 groups x 2 tensors = 256 units (1 iter/thread)
  {
    const int i = tid;
    const int which = i >> 7, j = i & 127;
    const int key = j >> 3, g = j & 7;
    const u16* src = which ? kvH : kvI;
    u16* dst = which ? Kh : Ki;
    *(u16x8*)(dst + key * KS + g * 8) =
        *(const u16x8*)(src + (size_t)(b * LIMG + key) * (2 * DD) + h * 64 + g * 8);
  }
  // V text transposed: 96 keys x 8 dh-groups; 16B load -> 8 LDS scalar writes
  for (int i = tid; i < 768; i += 256) {
    const int key = i >> 3, g = i & 7;
    u16x8 v = {};
    if (key < LTXT)
      v = *(const u16x8*)(kvT + (size_t)(b * LTXT + key) * (2 * DD) + DD + h * 64 + g * 8);
#pragma unroll
    for (int j = 0; j < 8; j++) Vt[(g * 8 + j) * VST + key] = v[j];
  }
  // V id / hair transposed: 32 keys x 8 groups x 2 tensors = 512 units
  for (int i = tid; i < 512; i += 256) {
    const int which = i >> 8, j2 = i & 255;
    const int key = j2 >> 3, g = j2 & 7;
    const u16* src = which ? kvH : kvI;
    u16* dst = which ? Vh : Vi;
    u16x8 v = {};
    if (key < LIMG)
      v = *(const u16x8*)(src + (size_t)(b * LIMG + key) * (2 * DD) + DD + h * 64 + g * 8);
#pragma unroll
    for (int j = 0; j < 8; j++) dst[(g * 8 + j) * VSI + key] = v[j];
  }
  __syncthreads();   // the ONLY block-wide barrier

  const int w  = tid >> 6;
  const int l  = tid & 63;
  const int q4 = l >> 4;
  const int lm = l & 15;
  u16* Pw = Pl[w];
  const int qbase = qt * 256 + w * 64;

#pragma unroll
  for (int m = 0; m < 4; m++) {
    const int qrow = qbase + m * 16;
    const u16* qp = Qb + ((size_t)(b * SS + qrow + lm)) * DD + h * 64 + q4 * 8;
    const bf16x8 qf0 = ld_bf8(qp);
    const bf16x8 qf1 = ld_bf8(qp + 32);

    f32x4 acc[4] = {};
    attn_branch<5, LTXT, 96, VST>(Kt, Vt, Pw, qf0, qf1, lm, q4, acc);
    attn_branch<1, LIMG, 32, VSI>(Ki, Vi, Pw, qf0, qf1, lm, q4, acc);
    attn_branch<1, LIMG, 32, VSI>(Kh, Vh, Pw, qf0, qf1, lm, q4, acc);

#pragma unroll
    for (int d = 0; d < 4; d++)
#pragma unroll
      for (int r = 0; r < 4; r++) {
        const int row = qrow + q4 * 4 + r;
        Ob[((size_t)(b * SS + row)) * DD + h * 64 + d * 16 + lm] = f2bf(acc[d][r]);
      }
  }
}

// =====================================================================
extern "C" void kernel_launch(void* const* d_in, const int* in_sizes, int n_in,
                              void* d_out, int out_size, void* d_ws, size_t ws_size,
                              hipStream_t stream) {
  (void)in_sizes; (void)n_in; (void)out_size; (void)ws_size;
  const float* hidden  = (const float*)d_in[0];
  const float* txt     = (const float*)d_in[1];
  const float* ids     = (const float*)d_in[2];
  const float* hair    = (const float*)d_in[3];
  const float* Wq      = (const float*)d_in[4];
  const float* Wk      = (const float*)d_in[5];
  const float* Wv      = (const float*)d_in[6];
  const float* Wo      = (const float*)d_in[7];
  const float* bo      = (const float*)d_in[8];
  const float* Wk_id   = (const float*)d_in[9];
  const float* Wv_id   = (const float*)d_in[10];
  const float* Wk_hair = (const float*)d_in[11];
  const float* Wv_hair = (const float*)d_in[12];
  float* out = (float*)d_out;

  char* ws = (char*)d_ws;
  size_t off = 0;
  auto alloc = [&](size_t bytes) {
    void* p = ws + off;
    off = (off + bytes + 255) & ~(size_t)255;
    return p;
  };
  u16* hiddenB = (u16*)alloc((size_t)MQ * DD * 2);       // 83.9 MB
  u16* QB      = (u16*)alloc((size_t)MQ * DD * 2);       // 83.9 MB
  u16* OB      = (u16*)alloc((size_t)MQ * DD * 2);       // 83.9 MB
  u16* WqT     = (u16*)alloc((size_t)DD * DD * 2);
  u16* WoT     = (u16*)alloc((size_t)DD * DD * 2);
  u16* WkvTt   = (u16*)alloc((size_t)2 * DD * CC * 2);
  u16* WkvTi   = (u16*)alloc((size_t)2 * DD * CC * 2);
  u16* WkvTh   = (u16*)alloc((size_t)2 * DD * CC * 2);
  u16* stT     = (u16*)alloc((size_t)MTXT * CC * 2);
  u16* stI     = (u16*)alloc((size_t)MIMG * CC * 2);
  u16* stH     = (u16*)alloc((size_t)MIMG * CC * 2);
  u16* kvT     = (u16*)alloc((size_t)MTXT * 2 * DD * 2);
  u16* kvI     = (u16*)alloc((size_t)MIMG * 2 * DD * 2);
  u16* kvH     = (u16*)alloc((size_t)MIMG * 2 * DD * 2);
  // total ~284 MB of workspace

  prep_kernel<<<dim3(1024, 12), 256, 0, stream>>>(
      hidden, txt, ids, hair, Wq, Wk, Wv, Wo, Wk_id, Wv_id, Wk_hair, Wv_hair,
      hiddenB, WqT, WoT, WkvTt, WkvTi, WkvTh, stT, stI, stH);

  // Q = hidden @ Wq, scaled by 1/sqrt(DH)=0.125 (exact in bf16)
  gemm_bf16_out<<<dim3(MQ / 128, DD / 128), 256, 0, stream>>>(
      hiddenB, WqT, QB, MQ, DD, DD, 0.125f);

  // K|V projections for all three branches
  gemm_kv3<<<dim3((MTXT + 127) / 128, (2 * DD) / 128, 3), 256, 0, stream>>>(
      stT, stI, stH, WkvTt, WkvTi, WkvTh, kvT, kvI, kvH, MTXT, MIMG, MIMG);

  // fused 3-branch attention -> summed O (bf16), 256 queries/block
  attn_kernel<<<dim3(SS / 256, HH, BB), 256, 0, stream>>>(QB, kvT, kvI, kvH, OB);

  // out = O_sum @ Wo + 3*bo (fp32)
  gemm_f32_bias<<<dim3(MQ / 128, DD / 128), 256, 0, stream>>>(
      OB, WoT, out, MQ, DD, DD, bo, 3.0f);
}